// Round 11
// baseline (507.441 us; speedup 1.0000x reference)
//
#include <hip/hip_runtime.h>
#include <hip/hip_fp16.h>

typedef unsigned int u32;
typedef unsigned short u16;
typedef _Float16 half2_t __attribute__((ext_vector_type(2)));

__device__ __forceinline__ u32 encf(float f){ u32 u=__float_as_uint(f); return (u&0x80000000u)? ~u : (u|0x80000000u); }
__device__ __forceinline__ float decf(u32 u){ return (u&0x80000000u)? __uint_as_float(u&0x7fffffffu) : __uint_as_float(~u); }

__device__ __forceinline__ float fast_tanh(float x){
  x = fminf(fmaxf(x, -15.f), 15.f);
  float e = __expf(2.f*x);
  return (e - 1.f) * __builtin_amdgcn_rcpf(e + 1.f);
}
__device__ __forceinline__ float fast_sigmoid(float x){
  x = fminf(fmaxf(x, -15.f), 15.f);
  return __builtin_amdgcn_rcpf(1.f + __expf(-x));
}

// Base-voxel index, bit-exact with reference: idx = floor(points + 1.0f); ix = idx-1.
__device__ __forceinline__ int base_ix(float p){
  return (int)floorf(p + 1.0f) - 1;   // in [0,254] for p in [0,255)
}

__device__ __forceinline__ half2_t h2cast(u32 u){ return __builtin_bit_cast(half2_t, u); }
__device__ __forceinline__ half2_t pk(float a, float b){
  return __builtin_bit_cast(half2_t, __builtin_amdgcn_cvt_pkrtz(a, b));
}
__device__ __forceinline__ float dot2(half2_t a, half2_t b, float c){
  return __builtin_amdgcn_fdot2(a, b, c, false);
}

// ---- repack f32 channel-major -> fp16 voxel-major (16B/voxel), 4 voxels/thread
// Also emits ch7 dilated over (y±1, z±1) as ushort4 (per-axis clamp).
__global__ __launch_bounds__(256) void repack16(const float* __restrict__ g,
                                                uint4* __restrict__ rg,
                                                ushort4* __restrict__ zy4){
  u32 t = blockIdx.x*256u + threadIdx.x;     // 16384 x 256 threads, 4 voxels each
  u32 v0 = t << 2;
  const float4* gv = (const float4*)g;
  float4 C[8];
  #pragma unroll
  for (int c=0;c<8;c++) C[c] = gv[((u32)c<<22) + t];

  #pragma unroll
  for (int k=0;k<4;k++){
    float a[8];
    #pragma unroll
    for (int c=0;c<8;c++) a[c] = ((const float*)&C[c])[k];
    __half2 p0 = __floats2half2_rn(a[0],a[1]);
    __half2 p1 = __floats2half2_rn(a[2],a[3]);
    __half2 p2 = __floats2half2_rn(a[4],a[5]);
    __half2 p3 = __floats2half2_rn(a[6],a[7]);
    uint4 o;
    o.x=*(const u32*)&p0; o.y=*(const u32*)&p1; o.z=*(const u32*)&p2; o.w=*(const u32*)&p3;
    rg[v0+k]=o;
  }

  // (y,z)-dilated ch7 for voxels v0..v0+3 (all share one z-row segment)
  u32 z0 = v0 & 255u;
  u32 y  = (v0>>8) & 255u;
  const float* g7 = g + ((size_t)7u<<24);
  float zmax[4] = {-3.0e38f,-3.0e38f,-3.0e38f,-3.0e38f};
  #pragma unroll
  for (int r=0;r<3;r++){
    int yy = (int)y + r - 1;
    u32 ro = (yy<0 || yy>255)? v0 : (u32)((int)v0 + (r-1)*256);
    float4 f = (r==1)? C[7] : *(const float4*)(g7 + ro);
    float e0 = (z0==0u)?   f.x : g7[ro-1u];
    float e5 = (z0==252u)? f.w : g7[ro+4u];
    float e[6] = {e0, f.x, f.y, f.z, f.w, e5};
    #pragma unroll
    for (int k=0;k<4;k++)
      zmax[k] = fmaxf(zmax[k], fmaxf(e[k], fmaxf(e[k+1], e[k+2])));
  }
  ushort4 zo;
  zo.x = __half_as_ushort(__float2half_rn(zmax[0]));
  zo.y = __half_as_ushort(__float2half_rn(zmax[1]));
  zo.z = __half_as_ushort(__float2half_rn(zmax[2]));
  zo.w = __half_as_ushort(__float2half_rn(zmax[3]));
  zy4[t] = zo;
}

// ---- counting sort by 8^3-voxel cell (32768 cells) --------------------------
__device__ __forceinline__ u32 cell_id(int ix, int iy, int iz){
  return ((u32)(ix>>3)<<10) | ((u32)(iy>>3)<<5) | (u32)(iz>>3);
}

__global__ __launch_bounds__(256) void hist(const float* __restrict__ pts,
                                            u32* __restrict__ cnt, int n){
  for (int i = blockIdx.x*blockDim.x + threadIdx.x; i < n; i += gridDim.x*blockDim.x){
    int ix = base_ix(pts[3*i]);
    int iy = base_ix(pts[3*i+1]);
    int iz = base_ix(pts[3*i+2]);
    atomicAdd(&cnt[cell_id(ix,iy,iz)], 1u);
  }
}

// one-block exclusive scan of 32768 = 1024 x 32
__global__ __launch_bounds__(1024) void scan32k(const u32* __restrict__ cnt,
                                                u32* __restrict__ ofs){
  __shared__ u32 sums[1024];
  int t = threadIdx.x;
  u32 loc[32];
  u32 s = 0;
  #pragma unroll
  for (int k=0;k<32;k++){ loc[k] = cnt[t*32+k]; s += loc[k]; }
  sums[t] = s;
  __syncthreads();
  for (int off=1; off<1024; off<<=1){
    u32 v = (t>=off)? sums[t-off] : 0u;
    __syncthreads();
    sums[t] += v;
    __syncthreads();
  }
  u32 run = (t>0)? sums[t-1] : 0u;
  #pragma unroll
  for (int k=0;k<32;k++){ ofs[t*32+k] = run; run += loc[k]; }
}

// ---- scatter + fused per-point max of (x,y,z)-dilated ch7 -------------------
__global__ __launch_bounds__(256) void scatter_max(const float* __restrict__ pts,
                                                   u32* __restrict__ ofs,
                                                   const u16* __restrict__ zy,
                                                   float4* __restrict__ srt,
                                                   u32* __restrict__ wmax, int n){
  __shared__ float red[4];
  float m = -3.0e38f;
  for (int i = blockIdx.x*blockDim.x + threadIdx.x; i < n; i += gridDim.x*blockDim.x){
    float px = pts[3*i], py = pts[3*i+1], pz = pts[3*i+2];
    int ix = base_ix(px), iy = base_ix(py), iz = base_ix(pz);
    u32 r = atomicAdd(&ofs[cell_id(ix,iy,iz)], 1u);
    srt[r] = make_float4(px, py, pz, __uint_as_float((u32)i));
    u32 cb = ((u32)ix<<16) | ((u32)iy<<8) | (u32)iz;
    u32 xm = (ix==0)? cb : cb - 65536u;      // ix <= 254, so ix+1 is always valid
    float a = __half2float(__ushort_as_half(zy[xm]));
    float b = __half2float(__ushort_as_half(zy[cb]));
    float c = __half2float(__ushort_as_half(zy[cb + 65536u]));
    m = fmaxf(m, fmaxf(a, fmaxf(b, c)));
  }
  #pragma unroll
  for (int o=32;o>=1;o>>=1) m = fmaxf(m, __shfl_xor(m, o));
  int wid = threadIdx.x >> 6;
  if ((threadIdx.x & 63)==0) red[wid] = m;
  __syncthreads();
  if (threadIdx.x == 0){
    float r2 = fmaxf(fmaxf(red[0],red[1]), fmaxf(red[2],red[3]));
    atomicMax(wmax, encf(r2));
  }
}

// ---- pack all weights to fp16 pairs (runs AFTER scatter_max: folds inv) -----
// layout (u32 units): WC2 [27][4][8] @0 | W1P [8][32] @864 | W2P [20][16] @1120
//                     W3P [12][8] @1440 | W4P [8][8] @1536 | WSP[4] @1600 | WOP[4] @1604
__global__ __launch_bounds__(256) void packw(const float* __restrict__ Wc,
                                             const float* __restrict__ W1,
                                             const float* __restrict__ W2,
                                             const float* __restrict__ W3,
                                             const float* __restrict__ W4,
                                             const float* __restrict__ Ws,
                                             const float* __restrict__ Wo,
                                             const u32* __restrict__ wmax,
                                             u32* __restrict__ dst){
  int t = blockIdx.x*256 + threadIdx.x;
  if (t >= 1608) return;
  float inv = 1.0f / (decf(*wmax) + 1e-9f);
  float w0, w1;
  if (t < 864){
    int j = t & 7, p = (t>>3) & 3, kk = t>>5;
    w0 = Wc[(kk*8 + 2*p)*8 + j];
    w1 = Wc[(kk*8 + 2*p+1)*8 + j];
    if (p == 3){  // c=7 row: fold the count-normalization scale
      w1 = fminf(fmaxf(w1*inv, -60000.f), 60000.f);
    }
  } else if (t < 1120){
    int u = t - 864; int j = u & 31, p = u >> 5;
    w0 = W1[(2*p)*32 + j]; w1 = W1[(2*p+1)*32 + j];
  } else if (t < 1440){
    int u = t - 1120; int j = u & 15, p = u >> 4;
    w0 = W2[(2*p)*16 + j]; w1 = W2[(2*p+1)*16 + j];
  } else if (t < 1536){
    int u = t - 1440; int j = u & 7, p = u >> 3;
    w0 = W3[(2*p)*8 + j]; w1 = W3[(2*p+1)*8 + j];
  } else if (t < 1600){
    int u = t - 1536; int j = u & 7, p = u >> 3;
    w0 = W4[(2*p)*8 + j]; w1 = W4[(2*p+1)*8 + j];
  } else if (t < 1604){
    int p = t - 1600; w0 = Ws[2*p]; w1 = Ws[2*p+1];
  } else {
    int p = t - 1604; w0 = Wo[2*p]; w1 = Wo[2*p+1];
  }
  __half2 h = __floats2half2_rn(w0, w1);
  dst[t] = *(const u32*)&h;
}

// ---- pass 2: sorted points, load-use gather (high occupancy), dot2 MLP ------
// No launch_bounds VGPR cap: compiler minimizes regs -> 6-8 waves/SIMD to hide
// gather latency (r8-r10's 27-preload + 3-wave cap was latency-exposed).
__global__ __launch_bounds__(256) void kmain16(const float4* __restrict__ srt,
                                               const uint4* __restrict__ rg,
                                               const u32* __restrict__ wmax,
                                               const u32* __restrict__ wpk,
                                               float2* __restrict__ out, int n,
                                               const float* __restrict__ bc,
                                               const float* __restrict__ b1,
                                               const float* __restrict__ b2,
                                               const float* __restrict__ b3,
                                               const float* __restrict__ b4,
                                               const float* __restrict__ bs,
                                               const float* __restrict__ bo)
{
  // bijective XCD swizzle: consecutive sorted blocks -> same XCD L2
  u32 nwg = gridDim.x;
  u32 qq = nwg >> 3, rr = nwg & 7u;
  u32 xcd = blockIdx.x & 7u, sub = blockIdx.x >> 3;
  u32 bid = (xcd < rr ? xcd*(qq+1u) : rr*(qq+1u) + (xcd-rr)*qq) + sub;

  int j = (int)(bid*256u + threadIdx.x);
  if (j >= n) return;
  float inv = 1.0f / (decf(*wmax) + 1e-9f);
  float4 rec = srt[j];
  int i = (int)__float_as_uint(rec.w);

  int ix = base_ix(rec.x);
  int iy = base_ix(rec.y);
  int iz = base_ix(rec.z);
  int xs[3] = {max(ix-1,0), ix, min(ix+1,255)};
  int ys[3] = {max(iy-1,0), iy, min(iy+1,255)};
  int zs[3] = {max(iz-1,0), iz, min(iz+1,255)};

  // ctx pre-activation: acc = bc + sum_kk Wc_kk^T v_kk  (fp16 dot2, f32 accum)
  float acc[8];
  #pragma unroll
  for (int jj=0;jj<8;jj++) acc[jj] = bc[jj];

  float cen[8];

  #pragma unroll
  for (int a=0;a<3;a++)
  #pragma unroll
  for (int b=0;b<3;b++)
  #pragma unroll
  for (int d=0;d<3;d++){
    const int kk = (a*3+b)*3+d;
    uint4 qv = rg[((u32)xs[a]<<16) | ((u32)ys[b]<<8) | (u32)zs[d]];
    half2_t v0 = h2cast(qv.x);
    half2_t v1 = h2cast(qv.y);
    half2_t v2 = h2cast(qv.z);
    half2_t v3 = h2cast(qv.w);
    if (kk == 13){
      float2 f0 = __half22float2(*(const __half2*)&qv.x);
      float2 f1 = __half22float2(*(const __half2*)&qv.y);
      float2 f2 = __half22float2(*(const __half2*)&qv.z);
      float2 f3 = __half22float2(*(const __half2*)&qv.w);
      cen[0]=f0.x; cen[1]=f0.y; cen[2]=f1.x; cen[3]=f1.y;
      cen[4]=f2.x; cen[5]=f2.y; cen[6]=f3.x; cen[7]=f3.y*inv;
    }
    const u32* w = wpk + kk*32;
    #pragma unroll
    for (int jj=0;jj<8;jj++){
      float s = acc[jj];
      s = dot2(v0, h2cast(w[jj]),     s);
      s = dot2(v1, h2cast(w[8+jj]),   s);
      s = dot2(v2, h2cast(w[16+jj]),  s);
      s = dot2(v3, h2cast(w[24+jj]),  s);
      acc[jj] = s;
    }
  }

  // layernorm + tanh -> ctx
  float mean = 0.f;
  #pragma unroll
  for (int jj=0;jj<8;jj++) mean += acc[jj];
  mean *= 0.125f;
  float var = 0.f;
  #pragma unroll
  for (int jj=0;jj<8;jj++){ float d = acc[jj]-mean; var += d*d; }
  var *= 0.125f;
  float rs = rsqrtf(var + 1e-5f);

  half2_t cenp[4], ctxp[4];
  #pragma unroll
  for (int p=0;p<4;p++){
    cenp[p] = pk(cen[2*p], cen[2*p+1]);
    ctxp[p] = pk(fast_tanh((acc[2*p]-mean)*rs), fast_tanh((acc[2*p+1]-mean)*rs));
  }

  const u32* W1h = wpk + 864;
  const u32* W2h = wpk + 1120;
  const u32* W3h = wpk + 1440;
  const u32* W4h = wpk + 1536;

  half2_t h1p[16];
  #pragma unroll
  for (int p2=0;p2<16;p2++){
    float s0 = b1[2*p2], s1 = b1[2*p2+1];
    #pragma unroll
    for (int p=0;p<4;p++){
      s0 = dot2(cenp[p], h2cast(W1h[p*32 + 2*p2]),     s0);
      s1 = dot2(cenp[p], h2cast(W1h[p*32 + 2*p2+1]),   s1);
      s0 = dot2(ctxp[p], h2cast(W1h[(4+p)*32 + 2*p2]), s0);
      s1 = dot2(ctxp[p], h2cast(W1h[(4+p)*32 + 2*p2+1]), s1);
    }
    h1p[p2] = pk(fast_tanh(s0), fast_tanh(s1));
  }

  half2_t h2p[8];
  #pragma unroll
  for (int p2=0;p2<8;p2++){
    float s0 = b2[2*p2], s1 = b2[2*p2+1];
    #pragma unroll
    for (int p=0;p<4;p++){
      s0 = dot2(cenp[p], h2cast(W2h[p*16 + 2*p2]),   s0);
      s1 = dot2(cenp[p], h2cast(W2h[p*16 + 2*p2+1]), s1);
    }
    #pragma unroll
    for (int p=0;p<16;p++){
      s0 = dot2(h1p[p], h2cast(W2h[(4+p)*16 + 2*p2]),   s0);
      s1 = dot2(h1p[p], h2cast(W2h[(4+p)*16 + 2*p2+1]), s1);
    }
    h2p[p2] = pk(fast_tanh(s0), fast_tanh(s1));
  }

  half2_t h3p[4];
  #pragma unroll
  for (int p2=0;p2<4;p2++){
    float s0 = b3[2*p2], s1 = b3[2*p2+1];
    #pragma unroll
    for (int p=0;p<4;p++){
      s0 = dot2(cenp[p], h2cast(W3h[p*8 + 2*p2]),   s0);
      s1 = dot2(cenp[p], h2cast(W3h[p*8 + 2*p2+1]), s1);
    }
    #pragma unroll
    for (int p=0;p<8;p++){
      s0 = dot2(h2p[p], h2cast(W3h[(4+p)*8 + 2*p2]),   s0);
      s1 = dot2(h2p[p], h2cast(W3h[(4+p)*8 + 2*p2+1]), s1);
    }
    h3p[p2] = pk(fast_tanh(s0), fast_tanh(s1));
  }

  half2_t h4p[4];
  #pragma unroll
  for (int p2=0;p2<4;p2++){
    float s0 = b4[2*p2], s1 = b4[2*p2+1];
    #pragma unroll
    for (int p=0;p<4;p++){
      s0 = dot2(cenp[p], h2cast(W4h[p*8 + 2*p2]),   s0);
      s1 = dot2(cenp[p], h2cast(W4h[p*8 + 2*p2+1]), s1);
      s0 = dot2(h3p[p], h2cast(W4h[(4+p)*8 + 2*p2]),   s0);
      s1 = dot2(h3p[p], h2cast(W4h[(4+p)*8 + 2*p2+1]), s1);
    }
    h4p[p2] = pk(fast_tanh(s0), fast_tanh(s1));
  }

  float ssdf = bs[0], socc = bo[0];
  #pragma unroll
  for (int p=0;p<4;p++){
    ssdf = dot2(h4p[p], h2cast(wpk[1600+p]), ssdf);
    socc = dot2(h4p[p], h2cast(wpk[1604+p]), socc);
  }
  out[i] = make_float2(fast_tanh(ssdf), fast_sigmoid(socc));
}

// ---- fallback path (round-3): direct channel-major gather, f32 math ---------
__device__ __forceinline__ void mlp_tail_f32(const float* __restrict__ cen,
                                             const float* __restrict__ acc0,
                                             float2* __restrict__ out, int i,
                                             const float* __restrict__ W1, const float* __restrict__ b1,
                                             const float* __restrict__ W2, const float* __restrict__ b2,
                                             const float* __restrict__ W3, const float* __restrict__ b3,
                                             const float* __restrict__ W4, const float* __restrict__ b4,
                                             const float* __restrict__ Ws, const float* __restrict__ bs,
                                             const float* __restrict__ Wo, const float* __restrict__ bo)
{
  float mean = 0.f;
  #pragma unroll
  for (int j=0;j<8;j++) mean += acc0[j];
  mean *= 0.125f;
  float var = 0.f;
  #pragma unroll
  for (int j=0;j<8;j++){ float t = acc0[j]-mean; var += t*t; }
  var *= 0.125f;
  float rs = rsqrtf(var + 1e-5f);
  float ctx[8];
  #pragma unroll
  for (int j=0;j<8;j++) ctx[j] = fast_tanh((acc0[j]-mean)*rs);
  float h1[32];
  #pragma unroll
  for (int j=0;j<32;j++){
    float s = b1[j];
    #pragma unroll
    for (int c=0;c<8;c++) s = fmaf(cen[c], W1[c*32 + j], s);
    #pragma unroll
    for (int c=0;c<8;c++) s = fmaf(ctx[c], W1[(8+c)*32 + j], s);
    h1[j] = fast_tanh(s);
  }
  float h2[16];
  #pragma unroll
  for (int j=0;j<16;j++){
    float s = b2[j];
    #pragma unroll
    for (int c=0;c<8;c++) s = fmaf(cen[c], W2[c*16 + j], s);
    #pragma unroll
    for (int c=0;c<32;c++) s = fmaf(h1[c], W2[(8+c)*16 + j], s);
    h2[j] = fast_tanh(s);
  }
  float h3[8];
  #pragma unroll
  for (int j=0;j<8;j++){
    float s = b3[j];
    #pragma unroll
    for (int c=0;c<8;c++) s = fmaf(cen[c], W3[c*8 + j], s);
    #pragma unroll
    for (int c=0;c<16;c++) s = fmaf(h2[c], W3[(8+c)*8 + j], s);
    h3[j] = fast_tanh(s);
  }
  float h4[8];
  #pragma unroll
  for (int j=0;j<8;j++){
    float s = b4[j];
    #pragma unroll
    for (int c=0;c<8;c++) s = fmaf(cen[c], W4[c*8 + j], s);
    #pragma unroll
    for (int c=0;c<8;c++) s = fmaf(h3[c], W4[(8+c)*8 + j], s);
    h4[j] = fast_tanh(s);
  }
  float ssdf = bs[0];
  float socc = bo[0];
  #pragma unroll
  for (int c=0;c<8;c++){
    ssdf = fmaf(h4[c], Ws[c], ssdf);
    socc = fmaf(h4[c], Wo[c], socc);
  }
  out[i] = make_float2(fast_tanh(ssdf), fast_sigmoid(socc));
}

__global__ __launch_bounds__(256) void kmax_direct(const float* __restrict__ pts,
                                                   const float* __restrict__ g7,
                                                   u32* __restrict__ wmax, int n){
  float m = -3.0e38f;
  for (int i = blockIdx.x*blockDim.x + threadIdx.x; i < n; i += gridDim.x*blockDim.x){
    int ix = base_ix(pts[3*i]);
    int iy = base_ix(pts[3*i+1]);
    int iz = base_ix(pts[3*i+2]);
    int xs[3] = {max(ix-1,0), ix, min(ix+1,255)};
    int ys[3] = {max(iy-1,0), iy, min(iy+1,255)};
    int zs[3] = {max(iz-1,0), iz, min(iz+1,255)};
    #pragma unroll
    for (int a=0;a<3;a++)
    #pragma unroll
    for (int b=0;b<3;b++){
      u32 rb = ((u32)xs[a]<<16) | ((u32)ys[b]<<8);
      #pragma unroll
      for (int d=0;d<3;d++) m = fmaxf(m, g7[rb + (u32)zs[d]]);
    }
  }
  #pragma unroll
  for (int o=32;o>=1;o>>=1) m = fmaxf(m, __shfl_xor(m, o));
  if ((threadIdx.x & 63)==0) atomicMax(wmax, encf(m));
}

__global__ __launch_bounds__(256) void kmain_direct(const float* __restrict__ pts,
                                                    const float* __restrict__ g,
                                                    const u32* __restrict__ wmax,
                                                    float2* __restrict__ out, int n,
                                                    const float* __restrict__ Wc, const float* __restrict__ bc,
                                                    const float* __restrict__ W1, const float* __restrict__ b1,
                                                    const float* __restrict__ W2, const float* __restrict__ b2,
                                                    const float* __restrict__ W3, const float* __restrict__ b3,
                                                    const float* __restrict__ W4, const float* __restrict__ b4,
                                                    const float* __restrict__ Ws, const float* __restrict__ bs,
                                                    const float* __restrict__ Wo, const float* __restrict__ bo)
{
  int i = blockIdx.x*256 + threadIdx.x;
  if (i >= n) return;
  float inv = 1.0f / (decf(*wmax) + 1e-9f);
  int ix = base_ix(pts[3*i]);
  int iy = base_ix(pts[3*i+1]);
  int iz = base_ix(pts[3*i+2]);
  int xs[3] = {max(ix-1,0), ix, min(ix+1,255)};
  int ys[3] = {max(iy-1,0), iy, min(iy+1,255)};
  int zs[3] = {max(iz-1,0), iz, min(iz+1,255)};
  u32 cb = ((u32)ix<<16) | ((u32)iy<<8) | (u32)iz;
  float cen[8];
  #pragma unroll
  for (int c=0;c<8;c++) cen[c] = g[((u32)c<<24) + cb];
  cen[7] *= inv;
  float acc[8];
  #pragma unroll
  for (int j=0;j<8;j++) acc[j] = bc[j];
  #pragma unroll
  for (int a=0;a<3;a++)
  #pragma unroll
  for (int b=0;b<3;b++)
  #pragma unroll
  for (int d=0;d<3;d++){
    const int kk = (a*3+b)*3+d;
    u32 vb = ((u32)xs[a]<<16) | ((u32)ys[b]<<8) | (u32)zs[d];
    float v[8];
    #pragma unroll
    for (int c=0;c<8;c++) v[c] = g[((u32)c<<24) + vb];
    v[7] *= inv;
    #pragma unroll
    for (int c=0;c<8;c++)
      #pragma unroll
      for (int j=0;j<8;j++)
        acc[j] = fmaf(v[c], Wc[(kk*8+c)*8 + j], acc[j]);
  }
  mlp_tail_f32(cen, acc, out, i, W1,b1,W2,b2,W3,b3,W4,b4,Ws,bs,Wo,bo);
}

extern "C" void kernel_launch(void* const* d_in, const int* in_sizes, int n_in,
                              void* d_out, int out_size, void* d_ws, size_t ws_size,
                              hipStream_t stream)
{
  const float* pts  = (const float*)d_in[0];
  const float* grid = (const float*)d_in[1];
  int n = in_sizes[0] / 3;

  const size_t NV       = (size_t)1 << 24;
  const size_t RG_BYTES = NV * 16;                   // 256 MiB fp16 voxel-major
  const size_t SL_BYTES = NV * 2;                    // 32 MiB dilation slab
  const size_t SRT_BYTES= (size_t)n * 16;            // 16 MiB sorted records
  const size_t CNT_BYTES= 32768 * 4;
  const size_t PK_BYTES = 8192;                      // packed fp16 weights
  const size_t NEED     = RG_BYTES + SL_BYTES + SRT_BYTES + 2*CNT_BYTES + 64 + PK_BYTES;

  if (ws_size >= NEED){
    char* base = (char*)d_ws;
    uint4*   rg   = (uint4*)base;
    u16*     zy   = (u16*)(base + RG_BYTES);
    float4*  srt  = (float4*)(base + RG_BYTES + SL_BYTES);
    u32*     cnt  = (u32*)(base + RG_BYTES + SL_BYTES + SRT_BYTES);
    u32*     ofs  = (u32*)(base + RG_BYTES + SL_BYTES + SRT_BYTES + CNT_BYTES);
    u32*     wmax = (u32*)(base + RG_BYTES + SL_BYTES + SRT_BYTES + 2*CNT_BYTES);
    u32*     wpk  = (u32*)(base + RG_BYTES + SL_BYTES + SRT_BYTES + 2*CNT_BYTES + 64);

    hipMemsetAsync(cnt, 0, CNT_BYTES, stream);
    hipMemsetAsync(wmax, 0, 64, stream);
    repack16<<<16384, 256, 0, stream>>>(grid, rg, (ushort4*)zy);
    hist<<<2048, 256, 0, stream>>>(pts, cnt, n);
    scan32k<<<1, 1024, 0, stream>>>(cnt, ofs);
    scatter_max<<<2048, 256, 0, stream>>>(pts, ofs, zy, srt, wmax, n);
    packw<<<7, 256, 0, stream>>>((const float*)d_in[2], (const float*)d_in[4],
                                 (const float*)d_in[6], (const float*)d_in[8],
                                 (const float*)d_in[10], (const float*)d_in[12],
                                 (const float*)d_in[14], wmax, wpk);
    kmain16<<<(n+255)/256, 256, 0, stream>>>(srt, rg, wmax, wpk, (float2*)d_out, n,
        (const float*)d_in[3],  (const float*)d_in[5],
        (const float*)d_in[7],  (const float*)d_in[9],
        (const float*)d_in[11], (const float*)d_in[13],
        (const float*)d_in[15]);
  } else {
    u32* wmax = (u32*)d_ws;
    hipMemsetAsync(wmax, 0, 64, stream);
    kmax_direct<<<2048, 256, 0, stream>>>(pts, grid + ((size_t)7<<24), wmax, n);
    kmain_direct<<<(n+255)/256, 256, 0, stream>>>(pts, grid, wmax, (float2*)d_out, n,
        (const float*)d_in[2],  (const float*)d_in[3],
        (const float*)d_in[4],  (const float*)d_in[5],
        (const float*)d_in[6],  (const float*)d_in[7],
        (const float*)d_in[8],  (const float*)d_in[9],
        (const float*)d_in[10], (const float*)d_in[11],
        (const float*)d_in[12], (const float*)d_in[13],
        (const float*)d_in[14], (const float*)d_in[15]);
  }
}

// Round 12
// 476.207 us; speedup vs baseline: 1.0656x; 1.0656x over previous
//
#include <hip/hip_runtime.h>
#include <hip/hip_fp16.h>

typedef unsigned int u32;
typedef unsigned short u16;
typedef _Float16 half2_t __attribute__((ext_vector_type(2)));

__device__ __forceinline__ u32 encf(float f){ u32 u=__float_as_uint(f); return (u&0x80000000u)? ~u : (u|0x80000000u); }
__device__ __forceinline__ float decf(u32 u){ return (u&0x80000000u)? __uint_as_float(u&0x7fffffffu) : __uint_as_float(~u); }

__device__ __forceinline__ float fast_tanh(float x){
  x = fminf(fmaxf(x, -15.f), 15.f);
  float e = __expf(2.f*x);
  return (e - 1.f) * __builtin_amdgcn_rcpf(e + 1.f);
}
__device__ __forceinline__ float fast_sigmoid(float x){
  x = fminf(fmaxf(x, -15.f), 15.f);
  return __builtin_amdgcn_rcpf(1.f + __expf(-x));
}

// Base-voxel index, bit-exact with reference: idx = floor(points + 1.0f); ix = idx-1.
__device__ __forceinline__ int base_ix(float p){
  return (int)floorf(p + 1.0f) - 1;   // in [0,254] for p in [0,255)
}

__device__ __forceinline__ half2_t h2cast(u32 u){ return __builtin_bit_cast(half2_t, u); }
__device__ __forceinline__ half2_t pk(float a, float b){
  return __builtin_bit_cast(half2_t, __builtin_amdgcn_cvt_pkrtz(a, b));
}
__device__ __forceinline__ float dot2(half2_t a, half2_t b, float c){
  return __builtin_amdgcn_fdot2(a, b, c, false);
}

__device__ __forceinline__ u32 cell_id(int ix, int iy, int iz){
  return ((u32)(ix>>3)<<10) | ((u32)(iy>>3)<<5) | (u32)(iz>>3);
}

// ---- fused: repack f32->fp16 voxel-major (blocks < 16384) + point histogram
// (blocks >= 16384). Hist rides in repack's memory-bound shadow.
__global__ __launch_bounds__(256) void repack_hist(const float* __restrict__ g,
                                                   uint4* __restrict__ rg,
                                                   ushort4* __restrict__ zy4,
                                                   const float* __restrict__ pts,
                                                   u32* __restrict__ cnt, int n){
  if (blockIdx.x >= 16384u){
    int base = (int)(blockIdx.x - 16384u)*256 + (int)threadIdx.x;
    for (int i = base; i < n; i += 1024*256){
      int ix = base_ix(pts[3*i]);
      int iy = base_ix(pts[3*i+1]);
      int iz = base_ix(pts[3*i+2]);
      atomicAdd(&cnt[cell_id(ix,iy,iz)], 1u);
    }
    return;
  }

  u32 t = blockIdx.x*256u + threadIdx.x;     // 16384 x 256 threads, 4 voxels each
  u32 v0 = t << 2;
  const float4* gv = (const float4*)g;
  float4 C[8];
  #pragma unroll
  for (int c=0;c<8;c++) C[c] = gv[((u32)c<<22) + t];

  #pragma unroll
  for (int k=0;k<4;k++){
    float a[8];
    #pragma unroll
    for (int c=0;c<8;c++) a[c] = ((const float*)&C[c])[k];
    __half2 p0 = __floats2half2_rn(a[0],a[1]);
    __half2 p1 = __floats2half2_rn(a[2],a[3]);
    __half2 p2 = __floats2half2_rn(a[4],a[5]);
    __half2 p3 = __floats2half2_rn(a[6],a[7]);
    uint4 o;
    o.x=*(const u32*)&p0; o.y=*(const u32*)&p1; o.z=*(const u32*)&p2; o.w=*(const u32*)&p3;
    rg[v0+k]=o;
  }

  // (y,z)-dilated ch7 for voxels v0..v0+3 (all share one z-row segment)
  u32 z0 = v0 & 255u;
  u32 y  = (v0>>8) & 255u;
  const float* g7 = g + ((size_t)7u<<24);
  float zmax[4] = {-3.0e38f,-3.0e38f,-3.0e38f,-3.0e38f};
  #pragma unroll
  for (int r=0;r<3;r++){
    int yy = (int)y + r - 1;
    u32 ro = (yy<0 || yy>255)? v0 : (u32)((int)v0 + (r-1)*256);
    float4 f = (r==1)? C[7] : *(const float4*)(g7 + ro);
    float e0 = (z0==0u)?   f.x : g7[ro-1u];
    float e5 = (z0==252u)? f.w : g7[ro+4u];
    float e[6] = {e0, f.x, f.y, f.z, f.w, e5};
    #pragma unroll
    for (int k=0;k<4;k++)
      zmax[k] = fmaxf(zmax[k], fmaxf(e[k], fmaxf(e[k+1], e[k+2])));
  }
  ushort4 zo;
  zo.x = __half_as_ushort(__float2half_rn(zmax[0]));
  zo.y = __half_as_ushort(__float2half_rn(zmax[1]));
  zo.z = __half_as_ushort(__float2half_rn(zmax[2]));
  zo.w = __half_as_ushort(__float2half_rn(zmax[3]));
  zy4[t] = zo;
}

// one-block exclusive scan of 32768 = 1024 x 32
__global__ __launch_bounds__(1024) void scan32k(const u32* __restrict__ cnt,
                                                u32* __restrict__ ofs){
  __shared__ u32 sums[1024];
  int t = threadIdx.x;
  u32 loc[32];
  u32 s = 0;
  #pragma unroll
  for (int k=0;k<32;k++){ loc[k] = cnt[t*32+k]; s += loc[k]; }
  sums[t] = s;
  __syncthreads();
  for (int off=1; off<1024; off<<=1){
    u32 v = (t>=off)? sums[t-off] : 0u;
    __syncthreads();
    sums[t] += v;
    __syncthreads();
  }
  u32 run = (t>0)? sums[t-1] : 0u;
  #pragma unroll
  for (int k=0;k<32;k++){ ofs[t*32+k] = run; run += loc[k]; }
}

// ---- scatter + fused per-point max of (x,y,z)-dilated ch7 -------------------
__global__ __launch_bounds__(256) void scatter_max(const float* __restrict__ pts,
                                                   u32* __restrict__ ofs,
                                                   const u16* __restrict__ zy,
                                                   float4* __restrict__ srt,
                                                   u32* __restrict__ wmax, int n){
  __shared__ float red[4];
  float m = -3.0e38f;
  for (int i = blockIdx.x*blockDim.x + threadIdx.x; i < n; i += gridDim.x*blockDim.x){
    float px = pts[3*i], py = pts[3*i+1], pz = pts[3*i+2];
    int ix = base_ix(px), iy = base_ix(py), iz = base_ix(pz);
    u32 r = atomicAdd(&ofs[cell_id(ix,iy,iz)], 1u);
    srt[r] = make_float4(px, py, pz, __uint_as_float((u32)i));
    u32 cb = ((u32)ix<<16) | ((u32)iy<<8) | (u32)iz;
    u32 xm = (ix==0)? cb : cb - 65536u;      // ix <= 254, so ix+1 is always valid
    float a = __half2float(__ushort_as_half(zy[xm]));
    float b = __half2float(__ushort_as_half(zy[cb]));
    float c = __half2float(__ushort_as_half(zy[cb + 65536u]));
    m = fmaxf(m, fmaxf(a, fmaxf(b, c)));
  }
  #pragma unroll
  for (int o=32;o>=1;o>>=1) m = fmaxf(m, __shfl_xor(m, o));
  int wid = threadIdx.x >> 6;
  if ((threadIdx.x & 63)==0) red[wid] = m;
  __syncthreads();
  if (threadIdx.x == 0){
    float r2 = fmaxf(fmaxf(red[0],red[1]), fmaxf(red[2],red[3]));
    atomicMax(wmax, encf(r2));
  }
}

// ---- pack all weights to fp16 pairs (runs AFTER scatter_max: folds inv) -----
// layout (u32 units): WC2 [27][4][8] @0 | W1P [8][32] @864 | W2P [20][16] @1120
//                     W3P [12][8] @1440 | W4P [8][8] @1536 | WSP[4] @1600 | WOP[4] @1604
__global__ __launch_bounds__(256) void packw(const float* __restrict__ Wc,
                                             const float* __restrict__ W1,
                                             const float* __restrict__ W2,
                                             const float* __restrict__ W3,
                                             const float* __restrict__ W4,
                                             const float* __restrict__ Ws,
                                             const float* __restrict__ Wo,
                                             const u32* __restrict__ wmax,
                                             u32* __restrict__ dst){
  int t = blockIdx.x*256 + threadIdx.x;
  if (t >= 1608) return;
  float inv = 1.0f / (decf(*wmax) + 1e-9f);
  float w0, w1;
  if (t < 864){
    int j = t & 7, p = (t>>3) & 3, kk = t>>5;
    w0 = Wc[(kk*8 + 2*p)*8 + j];
    w1 = Wc[(kk*8 + 2*p+1)*8 + j];
    if (p == 3){  // c=7 row: fold the count-normalization scale
      w1 = fminf(fmaxf(w1*inv, -60000.f), 60000.f);
    }
  } else if (t < 1120){
    int u = t - 864; int j = u & 31, p = u >> 5;
    w0 = W1[(2*p)*32 + j]; w1 = W1[(2*p+1)*32 + j];
  } else if (t < 1440){
    int u = t - 1120; int j = u & 15, p = u >> 4;
    w0 = W2[(2*p)*16 + j]; w1 = W2[(2*p+1)*16 + j];
  } else if (t < 1536){
    int u = t - 1440; int j = u & 7, p = u >> 3;
    w0 = W3[(2*p)*8 + j]; w1 = W3[(2*p+1)*8 + j];
  } else if (t < 1600){
    int u = t - 1536; int j = u & 7, p = u >> 3;
    w0 = W4[(2*p)*8 + j]; w1 = W4[(2*p+1)*8 + j];
  } else if (t < 1604){
    int p = t - 1600; w0 = Ws[2*p]; w1 = Ws[2*p+1];
  } else {
    int p = t - 1604; w0 = Wo[2*p]; w1 = Wo[2*p+1];
  }
  __half2 h = __floats2half2_rn(w0, w1);
  dst[t] = *(const u32*)&h;
}

// ---- pass 2: sorted points, 27-voxel preload, fp16-dot2 MLP (round-10 best) --
__global__ __launch_bounds__(256,3) void kmain16(const float4* __restrict__ srt,
                                                 const uint4* __restrict__ rg,
                                                 const u32* __restrict__ wmax,
                                                 const u32* __restrict__ wpk,
                                                 float2* __restrict__ out, int n,
                                                 const float* __restrict__ bc,
                                                 const float* __restrict__ b1,
                                                 const float* __restrict__ b2,
                                                 const float* __restrict__ b3,
                                                 const float* __restrict__ b4,
                                                 const float* __restrict__ bs,
                                                 const float* __restrict__ bo)
{
  // bijective XCD swizzle: consecutive sorted blocks -> same XCD L2
  u32 nwg = gridDim.x;
  u32 qq = nwg >> 3, rr = nwg & 7u;
  u32 xcd = blockIdx.x & 7u, sub = blockIdx.x >> 3;
  u32 bid = (xcd < rr ? xcd*(qq+1u) : rr*(qq+1u) + (xcd-rr)*qq) + sub;

  int j = (int)(bid*256u + threadIdx.x);
  if (j >= n) return;
  float inv = 1.0f / (decf(*wmax) + 1e-9f);
  float4 rec = srt[j];
  int i = (int)__float_as_uint(rec.w);

  int ix = base_ix(rec.x);
  int iy = base_ix(rec.y);
  int iz = base_ix(rec.z);
  int xs[3] = {max(ix-1,0), ix, min(ix+1,255)};
  int ys[3] = {max(iy-1,0), iy, min(iy+1,255)};
  int zs[3] = {max(iz-1,0), iz, min(iz+1,255)};

  // issue ALL 27 voxel loads first (independent -> single latency window)
  uint4 qv[27];
  #pragma unroll
  for (int a=0;a<3;a++)
  #pragma unroll
  for (int b=0;b<3;b++)
  #pragma unroll
  for (int d=0;d<3;d++)
    qv[(a*3+b)*3+d] = rg[((u32)xs[a]<<16) | ((u32)ys[b]<<8) | (u32)zs[d]];

  // ctx pre-activation: acc = bc + sum_kk Wc_kk^T v_kk  (fp16 dot2, f32 accum)
  float acc[8];
  #pragma unroll
  for (int jj=0;jj<8;jj++) acc[jj] = bc[jj];

  #pragma unroll
  for (int kk=0;kk<27;kk++){
    half2_t v0 = h2cast(qv[kk].x);
    half2_t v1 = h2cast(qv[kk].y);
    half2_t v2 = h2cast(qv[kk].z);
    half2_t v3 = h2cast(qv[kk].w);
    const u32* w = wpk + kk*32;
    #pragma unroll
    for (int jj=0;jj<8;jj++){
      float s = acc[jj];
      s = dot2(v0, h2cast(w[jj]),     s);
      s = dot2(v1, h2cast(w[8+jj]),   s);
      s = dot2(v2, h2cast(w[16+jj]),  s);
      s = dot2(v3, h2cast(w[24+jj]),  s);
      acc[jj] = s;
    }
  }

  float cen[8];
  {
    uint4 qc = qv[13];
    float2 f0 = __half22float2(*(const __half2*)&qc.x);
    float2 f1 = __half22float2(*(const __half2*)&qc.y);
    float2 f2 = __half22float2(*(const __half2*)&qc.z);
    float2 f3 = __half22float2(*(const __half2*)&qc.w);
    cen[0]=f0.x; cen[1]=f0.y; cen[2]=f1.x; cen[3]=f1.y;
    cen[4]=f2.x; cen[5]=f2.y; cen[6]=f3.x; cen[7]=f3.y*inv;
  }

  // layernorm + tanh -> ctx
  float mean = 0.f;
  #pragma unroll
  for (int jj=0;jj<8;jj++) mean += acc[jj];
  mean *= 0.125f;
  float var = 0.f;
  #pragma unroll
  for (int jj=0;jj<8;jj++){ float d = acc[jj]-mean; var += d*d; }
  var *= 0.125f;
  float rs = rsqrtf(var + 1e-5f);

  half2_t cenp[4], ctxp[4];
  #pragma unroll
  for (int p=0;p<4;p++){
    cenp[p] = pk(cen[2*p], cen[2*p+1]);
    ctxp[p] = pk(fast_tanh((acc[2*p]-mean)*rs), fast_tanh((acc[2*p+1]-mean)*rs));
  }

  const u32* W1h = wpk + 864;
  const u32* W2h = wpk + 1120;
  const u32* W3h = wpk + 1440;
  const u32* W4h = wpk + 1536;

  half2_t h1p[16];
  #pragma unroll
  for (int p2=0;p2<16;p2++){
    float s0 = b1[2*p2], s1 = b1[2*p2+1];
    #pragma unroll
    for (int p=0;p<4;p++){
      s0 = dot2(cenp[p], h2cast(W1h[p*32 + 2*p2]),     s0);
      s1 = dot2(cenp[p], h2cast(W1h[p*32 + 2*p2+1]),   s1);
      s0 = dot2(ctxp[p], h2cast(W1h[(4+p)*32 + 2*p2]), s0);
      s1 = dot2(ctxp[p], h2cast(W1h[(4+p)*32 + 2*p2+1]), s1);
    }
    h1p[p2] = pk(fast_tanh(s0), fast_tanh(s1));
  }

  half2_t h2p[8];
  #pragma unroll
  for (int p2=0;p2<8;p2++){
    float s0 = b2[2*p2], s1 = b2[2*p2+1];
    #pragma unroll
    for (int p=0;p<4;p++){
      s0 = dot2(cenp[p], h2cast(W2h[p*16 + 2*p2]),   s0);
      s1 = dot2(cenp[p], h2cast(W2h[p*16 + 2*p2+1]), s1);
    }
    #pragma unroll
    for (int p=0;p<16;p++){
      s0 = dot2(h1p[p], h2cast(W2h[(4+p)*16 + 2*p2]),   s0);
      s1 = dot2(h1p[p], h2cast(W2h[(4+p)*16 + 2*p2+1]), s1);
    }
    h2p[p2] = pk(fast_tanh(s0), fast_tanh(s1));
  }

  half2_t h3p[4];
  #pragma unroll
  for (int p2=0;p2<4;p2++){
    float s0 = b3[2*p2], s1 = b3[2*p2+1];
    #pragma unroll
    for (int p=0;p<4;p++){
      s0 = dot2(cenp[p], h2cast(W3h[p*8 + 2*p2]),   s0);
      s1 = dot2(cenp[p], h2cast(W3h[p*8 + 2*p2+1]), s1);
    }
    #pragma unroll
    for (int p=0;p<8;p++){
      s0 = dot2(h2p[p], h2cast(W3h[(4+p)*8 + 2*p2]),   s0);
      s1 = dot2(h2p[p], h2cast(W3h[(4+p)*8 + 2*p2+1]), s1);
    }
    h3p[p2] = pk(fast_tanh(s0), fast_tanh(s1));
  }

  half2_t h4p[4];
  #pragma unroll
  for (int p2=0;p2<4;p2++){
    float s0 = b4[2*p2], s1 = b4[2*p2+1];
    #pragma unroll
    for (int p=0;p<4;p++){
      s0 = dot2(cenp[p], h2cast(W4h[p*8 + 2*p2]),   s0);
      s1 = dot2(cenp[p], h2cast(W4h[p*8 + 2*p2+1]), s1);
      s0 = dot2(h3p[p], h2cast(W4h[(4+p)*8 + 2*p2]),   s0);
      s1 = dot2(h3p[p], h2cast(W4h[(4+p)*8 + 2*p2+1]), s1);
    }
    h4p[p2] = pk(fast_tanh(s0), fast_tanh(s1));
  }

  float ssdf = bs[0], socc = bo[0];
  #pragma unroll
  for (int p=0;p<4;p++){
    ssdf = dot2(h4p[p], h2cast(wpk[1600+p]), ssdf);
    socc = dot2(h4p[p], h2cast(wpk[1604+p]), socc);
  }
  out[i] = make_float2(fast_tanh(ssdf), fast_sigmoid(socc));
}

// ---- fallback path (round-3): direct channel-major gather, f32 math ---------
__device__ __forceinline__ void mlp_tail_f32(const float* __restrict__ cen,
                                             const float* __restrict__ acc0,
                                             float2* __restrict__ out, int i,
                                             const float* __restrict__ W1, const float* __restrict__ b1,
                                             const float* __restrict__ W2, const float* __restrict__ b2,
                                             const float* __restrict__ W3, const float* __restrict__ b3,
                                             const float* __restrict__ W4, const float* __restrict__ b4,
                                             const float* __restrict__ Ws, const float* __restrict__ bs,
                                             const float* __restrict__ Wo, const float* __restrict__ bo)
{
  float mean = 0.f;
  #pragma unroll
  for (int j=0;j<8;j++) mean += acc0[j];
  mean *= 0.125f;
  float var = 0.f;
  #pragma unroll
  for (int j=0;j<8;j++){ float t = acc0[j]-mean; var += t*t; }
  var *= 0.125f;
  float rs = rsqrtf(var + 1e-5f);
  float ctx[8];
  #pragma unroll
  for (int j=0;j<8;j++) ctx[j] = fast_tanh((acc0[j]-mean)*rs);
  float h1[32];
  #pragma unroll
  for (int j=0;j<32;j++){
    float s = b1[j];
    #pragma unroll
    for (int c=0;c<8;c++) s = fmaf(cen[c], W1[c*32 + j], s);
    #pragma unroll
    for (int c=0;c<8;c++) s = fmaf(ctx[c], W1[(8+c)*32 + j], s);
    h1[j] = fast_tanh(s);
  }
  float h2[16];
  #pragma unroll
  for (int j=0;j<16;j++){
    float s = b2[j];
    #pragma unroll
    for (int c=0;c<8;c++) s = fmaf(cen[c], W2[c*16 + j], s);
    #pragma unroll
    for (int c=0;c<32;c++) s = fmaf(h1[c], W2[(8+c)*16 + j], s);
    h2[j] = fast_tanh(s);
  }
  float h3[8];
  #pragma unroll
  for (int j=0;j<8;j++){
    float s = b3[j];
    #pragma unroll
    for (int c=0;c<8;c++) s = fmaf(cen[c], W3[c*8 + j], s);
    #pragma unroll
    for (int c=0;c<16;c++) s = fmaf(h2[c], W3[(8+c)*8 + j], s);
    h3[j] = fast_tanh(s);
  }
  float h4[8];
  #pragma unroll
  for (int j=0;j<8;j++){
    float s = b4[j];
    #pragma unroll
    for (int c=0;c<8;c++) s = fmaf(cen[c], W4[c*8 + j], s);
    #pragma unroll
    for (int c=0;c<8;c++) s = fmaf(h3[c], W4[(8+c)*8 + j], s);
    h4[j] = fast_tanh(s);
  }
  float ssdf = bs[0];
  float socc = bo[0];
  #pragma unroll
  for (int c=0;c<8;c++){
    ssdf = fmaf(h4[c], Ws[c], ssdf);
    socc = fmaf(h4[c], Wo[c], socc);
  }
  out[i] = make_float2(fast_tanh(ssdf), fast_sigmoid(socc));
}

__global__ __launch_bounds__(256) void kmax_direct(const float* __restrict__ pts,
                                                   const float* __restrict__ g7,
                                                   u32* __restrict__ wmax, int n){
  float m = -3.0e38f;
  for (int i = blockIdx.x*blockDim.x + threadIdx.x; i < n; i += gridDim.x*blockDim.x){
    int ix = base_ix(pts[3*i]);
    int iy = base_ix(pts[3*i+1]);
    int iz = base_ix(pts[3*i+2]);
    int xs[3] = {max(ix-1,0), ix, min(ix+1,255)};
    int ys[3] = {max(iy-1,0), iy, min(iy+1,255)};
    int zs[3] = {max(iz-1,0), iz, min(iz+1,255)};
    #pragma unroll
    for (int a=0;a<3;a++)
    #pragma unroll
    for (int b=0;b<3;b++){
      u32 rb = ((u32)xs[a]<<16) | ((u32)ys[b]<<8);
      #pragma unroll
      for (int d=0;d<3;d++) m = fmaxf(m, g7[rb + (u32)zs[d]]);
    }
  }
  #pragma unroll
  for (int o=32;o>=1;o>>=1) m = fmaxf(m, __shfl_xor(m, o));
  if ((threadIdx.x & 63)==0) atomicMax(wmax, encf(m));
}

__global__ __launch_bounds__(256) void kmain_direct(const float* __restrict__ pts,
                                                    const float* __restrict__ g,
                                                    const u32* __restrict__ wmax,
                                                    float2* __restrict__ out, int n,
                                                    const float* __restrict__ Wc, const float* __restrict__ bc,
                                                    const float* __restrict__ W1, const float* __restrict__ b1,
                                                    const float* __restrict__ W2, const float* __restrict__ b2,
                                                    const float* __restrict__ W3, const float* __restrict__ b3,
                                                    const float* __restrict__ W4, const float* __restrict__ b4,
                                                    const float* __restrict__ Ws, const float* __restrict__ bs,
                                                    const float* __restrict__ Wo, const float* __restrict__ bo)
{
  int i = blockIdx.x*256 + threadIdx.x;
  if (i >= n) return;
  float inv = 1.0f / (decf(*wmax) + 1e-9f);
  int ix = base_ix(pts[3*i]);
  int iy = base_ix(pts[3*i+1]);
  int iz = base_ix(pts[3*i+2]);
  int xs[3] = {max(ix-1,0), ix, min(ix+1,255)};
  int ys[3] = {max(iy-1,0), iy, min(iy+1,255)};
  int zs[3] = {max(iz-1,0), iz, min(iz+1,255)};
  u32 cb = ((u32)ix<<16) | ((u32)iy<<8) | (u32)iz;
  float cen[8];
  #pragma unroll
  for (int c=0;c<8;c++) cen[c] = g[((u32)c<<24) + cb];
  cen[7] *= inv;
  float acc[8];
  #pragma unroll
  for (int j=0;j<8;j++) acc[j] = bc[j];
  #pragma unroll
  for (int a=0;a<3;a++)
  #pragma unroll
  for (int b=0;b<3;b++)
  #pragma unroll
  for (int d=0;d<3;d++){
    const int kk = (a*3+b)*3+d;
    u32 vb = ((u32)xs[a]<<16) | ((u32)ys[b]<<8) | (u32)zs[d];
    float v[8];
    #pragma unroll
    for (int c=0;c<8;c++) v[c] = g[((u32)c<<24) + vb];
    v[7] *= inv;
    #pragma unroll
    for (int c=0;c<8;c++)
      #pragma unroll
      for (int j=0;j<8;j++)
        acc[j] = fmaf(v[c], Wc[(kk*8+c)*8 + j], acc[j]);
  }
  mlp_tail_f32(cen, acc, out, i, W1,b1,W2,b2,W3,b3,W4,b4,Ws,bs,Wo,bo);
}

extern "C" void kernel_launch(void* const* d_in, const int* in_sizes, int n_in,
                              void* d_out, int out_size, void* d_ws, size_t ws_size,
                              hipStream_t stream)
{
  const float* pts  = (const float*)d_in[0];
  const float* grid = (const float*)d_in[1];
  int n = in_sizes[0] / 3;

  const size_t NV       = (size_t)1 << 24;
  const size_t RG_BYTES = NV * 16;                   // 256 MiB fp16 voxel-major
  const size_t SL_BYTES = NV * 2;                    // 32 MiB dilation slab
  const size_t SRT_BYTES= (size_t)n * 16;            // 16 MiB sorted records
  const size_t CNT_BYTES= 32768 * 4;
  const size_t PK_BYTES = 8192;                      // packed fp16 weights
  const size_t NEED     = RG_BYTES + SL_BYTES + SRT_BYTES + 2*CNT_BYTES + 64 + PK_BYTES;

  if (ws_size >= NEED){
    char* base = (char*)d_ws;
    uint4*   rg   = (uint4*)base;
    u16*     zy   = (u16*)(base + RG_BYTES);
    float4*  srt  = (float4*)(base + RG_BYTES + SL_BYTES);
    u32*     cnt  = (u32*)(base + RG_BYTES + SL_BYTES + SRT_BYTES);
    u32*     ofs  = (u32*)(base + RG_BYTES + SL_BYTES + SRT_BYTES + CNT_BYTES);
    u32*     wmax = (u32*)(base + RG_BYTES + SL_BYTES + SRT_BYTES + 2*CNT_BYTES);
    u32*     wpk  = (u32*)(base + RG_BYTES + SL_BYTES + SRT_BYTES + 2*CNT_BYTES + 64);

    hipMemsetAsync(cnt, 0, CNT_BYTES, stream);
    hipMemsetAsync(wmax, 0, 64, stream);
    repack_hist<<<16384 + 1024, 256, 0, stream>>>(grid, rg, (ushort4*)zy, pts, cnt, n);
    scan32k<<<1, 1024, 0, stream>>>(cnt, ofs);
    scatter_max<<<2048, 256, 0, stream>>>(pts, ofs, zy, srt, wmax, n);
    packw<<<7, 256, 0, stream>>>((const float*)d_in[2], (const float*)d_in[4],
                                 (const float*)d_in[6], (const float*)d_in[8],
                                 (const float*)d_in[10], (const float*)d_in[12],
                                 (const float*)d_in[14], wmax, wpk);
    kmain16<<<(n+255)/256, 256, 0, stream>>>(srt, rg, wmax, wpk, (float2*)d_out, n,
        (const float*)d_in[3],  (const float*)d_in[5],
        (const float*)d_in[7],  (const float*)d_in[9],
        (const float*)d_in[11], (const float*)d_in[13],
        (const float*)d_in[15]);
  } else {
    u32* wmax = (u32*)d_ws;
    hipMemsetAsync(wmax, 0, 64, stream);
    kmax_direct<<<2048, 256, 0, stream>>>(pts, grid + ((size_t)7<<24), wmax, n);
    kmain_direct<<<(n+255)/256, 256, 0, stream>>>(pts, grid, wmax, (float2*)d_out, n,
        (const float*)d_in[2],  (const float*)d_in[3],
        (const float*)d_in[4],  (const float*)d_in[5],
        (const float*)d_in[6],  (const float*)d_in[7],
        (const float*)d_in[8],  (const float*)d_in[9],
        (const float*)d_in[10], (const float*)d_in[11],
        (const float*)d_in[12], (const float*)d_in[13],
        (const float*)d_in[14], (const float*)d_in[15]);
  }
}